// Round 1
// baseline (82.658 us; speedup 1.0000x reference)
//
#include <hip/hip_runtime.h>
#include <stdint.h>

#define LL     2000
#define NBATCH 512
#define CIN    32
#define COUT   32
#define LPAD   2048   // padded l-stride for packed bits (uint2 per position)

// ---------------- kernel 1: pack weight signs --------------------------------
// 96 threads, one per (co,k). wb layout: wb[co*8 + k*2 + {0,1}] = {pos,neg} mask over ci.
__global__ __launch_bounds__(96) void pack_w_kernel(const float* __restrict__ w,
                                                    uint32_t* __restrict__ wb) {
    int t = threadIdx.x;
    if (t >= COUT * 3) return;
    int co = t / 3, k = t % 3;
    uint32_t p = 0, m = 0;
    #pragma unroll
    for (int ci = 0; ci < CIN; ++ci) {
        float v = w[(co * CIN + ci) * 3 + k];
        p |= ((uint32_t)(v > 0.0f)) << ci;
        m |= ((uint32_t)(v < 0.0f)) << ci;
    }
    wb[co * 8 + k * 2 + 0] = p;
    wb[co * 8 + k * 2 + 1] = m;
}

// ---------------- kernel 2: pack x signs --------------------------------------
// grid.x = n (512), 256 threads. Each thread handles 4 consecutive l via float4
// loads (coalesced 1KB/wave per ci iteration). Output: uint2 (pos,neg) per (n,l).
__global__ __launch_bounds__(256) void pack_x_kernel(const float* __restrict__ x,
                                                     uint32_t* __restrict__ xb) {
    const int n = blockIdx.x;
    const float* xn_ = x + (size_t)n * CIN * LL;
    uint32_t* row = xb + (size_t)n * LPAD * 2;

    for (int c4 = threadIdx.x; c4 < LL / 4; c4 += 256) {
        const int l0 = c4 * 4;
        uint32_t p0 = 0, p1 = 0, p2 = 0, p3 = 0;
        uint32_t m0 = 0, m1 = 0, m2 = 0, m3 = 0;
        #pragma unroll
        for (int ci = 0; ci < CIN; ++ci) {
            float4 v = *(const float4*)(xn_ + (size_t)ci * LL + l0);
            p0 |= ((uint32_t)(v.x > 0.0f)) << ci;
            m0 |= ((uint32_t)(v.x < 0.0f)) << ci;
            p1 |= ((uint32_t)(v.y > 0.0f)) << ci;
            m1 |= ((uint32_t)(v.y < 0.0f)) << ci;
            p2 |= ((uint32_t)(v.z > 0.0f)) << ci;
            m2 |= ((uint32_t)(v.z < 0.0f)) << ci;
            p3 |= ((uint32_t)(v.w > 0.0f)) << ci;
            m3 |= ((uint32_t)(v.w < 0.0f)) << ci;
        }
        uint4 s0 = make_uint4(p0, m0, p1, m1);
        uint4 s1 = make_uint4(p2, m2, p3, m3);
        *(uint4*)(row + (size_t)l0 * 2)     = s0;
        *(uint4*)(row + (size_t)l0 * 2 + 4) = s1;
    }
}

// ---------------- kernel 3: ternary conv via popcount -------------------------
// grid = (ceil(L/256), N). One thread per (n,l), computes all 32 output channels.
// Weight masks + o_scale are uniform in the co loop -> scalar loads.
__global__ __launch_bounds__(256) void conv_kernel(const uint32_t* __restrict__ xb,
                                                   const uint32_t* __restrict__ wb,
                                                   const float* __restrict__ osc,
                                                   const float* __restrict__ lsc,
                                                   float* __restrict__ out) {
    const int n = blockIdx.y;
    const int l = blockIdx.x * 256 + threadIdx.x;
    if (l >= LL) return;

    const uint32_t* row = xb + (size_t)n * LPAD * 2;
    uint2 xm = (l > 0)      ? *(const uint2*)(row + (size_t)(l - 1) * 2) : make_uint2(0u, 0u);
    uint2 xc =                *(const uint2*)(row + (size_t)l * 2);
    uint2 xq = (l < LL - 1) ? *(const uint2*)(row + (size_t)(l + 1) * 2) : make_uint2(0u, 0u);

    const float lscale = lsc[l];
    float* o = out + (size_t)n * COUT * LL + l;

    #pragma unroll 4
    for (int co = 0; co < COUT; ++co) {
        const uint32_t* wq = wb + co * 8;
        uint32_t wp0 = wq[0], wn0 = wq[1];
        uint32_t wp1 = wq[2], wn1 = wq[3];
        uint32_t wp2 = wq[4], wn2 = wq[5];

        // dot(sx, sw) over ci, taps: y[l] = bx[l-1]*w[k=0] + bx[l]*w[k=1] + bx[l+1]*w[k=2]
        int P = __popc(xm.x & wp0) + __popc(xm.y & wn0)
              + __popc(xc.x & wp1) + __popc(xc.y & wn1)
              + __popc(xq.x & wp2) + __popc(xq.y & wn2);
        int M = __popc(xm.x & wn0) + __popc(xm.y & wp0)
              + __popc(xc.x & wn1) + __popc(xc.y & wp1)
              + __popc(xq.x & wn2) + __popc(xq.y & wp2);

        o[(size_t)co * LL] = (float)(P - M) * osc[co] * lscale;
    }
}

extern "C" void kernel_launch(void* const* d_in, const int* in_sizes, int n_in,
                              void* d_out, int out_size, void* d_ws, size_t ws_size,
                              hipStream_t stream) {
    const float* x   = (const float*)d_in[0];
    const float* w   = (const float*)d_in[1];
    const float* osc = (const float*)d_in[2];
    const float* lsc = (const float*)d_in[3];
    float* out = (float*)d_out;

    uint32_t* wb = (uint32_t*)d_ws;                       // 1 KiB
    uint32_t* xb = (uint32_t*)((char*)d_ws + 1024);       // 512*2048*8 B = 8.4 MB

    pack_w_kernel<<<1, 96, 0, stream>>>(w, wb);
    pack_x_kernel<<<NBATCH, 256, 0, stream>>>(x, xb);
    conv_kernel<<<dim3((LL + 255) / 256, NBATCH), 256, 0, stream>>>(xb, wb, osc, lsc, out);
}

// Round 2
// 74.345 us; speedup vs baseline: 1.1118x; 1.1118x over previous
//
#include <hip/hip_runtime.h>
#include <stdint.h>

#define LL    2000
#define NB    512
#define CIN   32
#define COUT  32
#define TILE  1000   // l-positions per block (2 tiles per n)

// ---------------- kernel 1: pack weight signs --------------------------------
// wb[co*8 + k*2 + {0,1}] = {pos,neg} ci-mask for tap k.
__global__ __launch_bounds__(96) void pack_w_kernel(const float* __restrict__ w,
                                                    uint32_t* __restrict__ wb) {
    int t = threadIdx.x;
    if (t >= COUT * 3) return;
    int co = t / 3, k = t % 3;
    uint32_t p = 0, m = 0;
    #pragma unroll
    for (int ci = 0; ci < CIN; ++ci) {
        float v = w[(co * CIN + ci) * 3 + k];
        p |= ((uint32_t)(v > 0.0f)) << ci;
        m |= ((uint32_t)(v < 0.0f)) << ci;
    }
    wb[co * 8 + k * 2 + 0] = p;
    wb[co * 8 + k * 2 + 1] = m;
}

// ---------------- kernel 2: fused pack-x (LDS) + ternary conv -----------------
// grid = NB * (LL/TILE). Block handles (n, [l0, l0+TILE)).
// Packed pair for x-position q lives at LDS pair-index ld = q - l0 + 1
// (interleaved p,m). Main threads (t < TILE/4) pack 4 positions each; threads
// 250/251 pack the left/right halo. Conv phase: thread t computes l = l0+4t..+3
// for all 32 co, float4 stores.
__global__ __launch_bounds__(256) void fused_kernel(const float* __restrict__ x,
                                                    const uint32_t* __restrict__ wb,
                                                    const float* __restrict__ osc,
                                                    const float* __restrict__ lsc,
                                                    float* __restrict__ out) {
    __shared__ uint32_t sp[(TILE + 2) * 2];   // 8016 B

    const int n  = blockIdx.x >> 1;
    const int l0 = (blockIdx.x & 1) * TILE;
    const int t  = threadIdx.x;
    const float* xn = x + (size_t)n * (CIN * LL);

    if (t < TILE / 4) {
        const int l = l0 + t * 4;
        uint32_t p0 = 0, m0 = 0, p1 = 0, m1 = 0, p2 = 0, m2 = 0, p3 = 0, m3 = 0;
        #pragma unroll
        for (int ci = 0; ci < CIN; ++ci) {
            float4 v = *(const float4*)(xn + ci * LL + l);
            p0 |= ((uint32_t)(v.x > 0.0f)) << ci;  m0 |= ((uint32_t)(v.x < 0.0f)) << ci;
            p1 |= ((uint32_t)(v.y > 0.0f)) << ci;  m1 |= ((uint32_t)(v.y < 0.0f)) << ci;
            p2 |= ((uint32_t)(v.z > 0.0f)) << ci;  m2 |= ((uint32_t)(v.z < 0.0f)) << ci;
            p3 |= ((uint32_t)(v.w > 0.0f)) << ci;  m3 |= ((uint32_t)(v.w < 0.0f)) << ci;
        }
        // pair index ld = 4t+1 -> byte offset 32t+8: 8B-aligned, use uint2 writes
        uint32_t* dst = sp + 2 * (4 * t + 1);
        *(uint2*)(dst + 0) = make_uint2(p0, m0);
        *(uint2*)(dst + 2) = make_uint2(p1, m1);
        *(uint2*)(dst + 4) = make_uint2(p2, m2);
        *(uint2*)(dst + 6) = make_uint2(p3, m3);
    } else if (t == 250 || t == 251) {
        const bool right = (t == 251);
        const int l = right ? (l0 + TILE) : (l0 - 1);
        uint32_t p = 0, m = 0;
        if (l >= 0 && l < LL) {
            #pragma unroll
            for (int ci = 0; ci < CIN; ++ci) {
                float v = xn[ci * LL + l];
                p |= ((uint32_t)(v > 0.0f)) << ci;
                m |= ((uint32_t)(v < 0.0f)) << ci;
            }
        }
        const int ld = right ? (TILE + 1) : 0;
        *(uint2*)(sp + 2 * ld) = make_uint2(p, m);
    }
    __syncthreads();
    if (t >= TILE / 4) return;

    const int l = l0 + t * 4;
    // pairs ld = 4t .. 4t+5 -> bytes 32t..32t+47, 16B-aligned uint4 reads
    const uint4 a = *(const uint4*)(sp + 8 * t);       // (p,m)@l-1, (p,m)@l
    const uint4 b = *(const uint4*)(sp + 8 * t + 4);   // (p,m)@l+1, (p,m)@l+2
    const uint4 c = *(const uint4*)(sp + 8 * t + 8);   // (p,m)@l+3, (p,m)@l+4
    const float4 ls = *(const float4*)(lsc + l);
    float* o = out + (size_t)n * (COUT * LL) + l;

    #pragma unroll 4
    for (int co = 0; co < COUT; ++co) {
        const uint32_t wp0 = wb[co * 8 + 0], wn0 = wb[co * 8 + 1];
        const uint32_t wp1 = wb[co * 8 + 2], wn1 = wb[co * 8 + 3];
        const uint32_t wp2 = wb[co * 8 + 4], wn2 = wb[co * 8 + 5];
        const float os = osc[co];

        int d0 = __popc(a.x & wp0) + __popc(a.y & wn0)
               + __popc(a.z & wp1) + __popc(a.w & wn1)
               + __popc(b.x & wp2) + __popc(b.y & wn2)
               - __popc(a.x & wn0) - __popc(a.y & wp0)
               - __popc(a.z & wn1) - __popc(a.w & wp1)
               - __popc(b.x & wn2) - __popc(b.y & wp2);
        int d1 = __popc(a.z & wp0) + __popc(a.w & wn0)
               + __popc(b.x & wp1) + __popc(b.y & wn1)
               + __popc(b.z & wp2) + __popc(b.w & wn2)
               - __popc(a.z & wn0) - __popc(a.w & wp0)
               - __popc(b.x & wn1) - __popc(b.y & wp1)
               - __popc(b.z & wn2) - __popc(b.w & wp2);
        int d2 = __popc(b.x & wp0) + __popc(b.y & wn0)
               + __popc(b.z & wp1) + __popc(b.w & wn1)
               + __popc(c.x & wp2) + __popc(c.y & wn2)
               - __popc(b.x & wn0) - __popc(b.y & wp0)
               - __popc(b.z & wn1) - __popc(b.w & wp1)
               - __popc(c.x & wn2) - __popc(c.y & wp2);
        int d3 = __popc(b.z & wp0) + __popc(b.w & wn0)
               + __popc(c.x & wp1) + __popc(c.y & wn1)
               + __popc(c.z & wp2) + __popc(c.w & wn2)
               - __popc(b.z & wn0) - __popc(b.w & wp0)
               - __popc(c.x & wn1) - __popc(c.y & wp1)
               - __popc(c.z & wn2) - __popc(c.w & wp2);

        float4 r;
        r.x = (float)d0 * os * ls.x;
        r.y = (float)d1 * os * ls.y;
        r.z = (float)d2 * os * ls.z;
        r.w = (float)d3 * os * ls.w;
        *(float4*)(o + (size_t)co * LL) = r;
    }
}

extern "C" void kernel_launch(void* const* d_in, const int* in_sizes, int n_in,
                              void* d_out, int out_size, void* d_ws, size_t ws_size,
                              hipStream_t stream) {
    const float* x   = (const float*)d_in[0];
    const float* w   = (const float*)d_in[1];
    const float* osc = (const float*)d_in[2];
    const float* lsc = (const float*)d_in[3];
    float* out = (float*)d_out;

    uint32_t* wb = (uint32_t*)d_ws;   // 1 KiB used

    pack_w_kernel<<<1, 96, 0, stream>>>(w, wb);
    fused_kernel<<<NB * (LL / TILE), 256, 0, stream>>>(x, wb, osc, lsc, out);
}

// Round 3
// 59.703 us; speedup vs baseline: 1.3845x; 1.2453x over previous
//
#include <hip/hip_runtime.h>
#include <stdint.h>

#define LL   2000
#define NB   512
#define CIN  32
#define COUT 32
#define TILE 256
#define NT   8    // tiles per n (last covers 208 positions)

// ---------------- kernel 1: pack weight ternary masks ------------------------
// wb[co*8 + k*2 + {0,1}] = {nz, sign} ci-mask for tap k. (words 6,7 unused)
__global__ __launch_bounds__(96) void pack_w_kernel(const float* __restrict__ w,
                                                    uint32_t* __restrict__ wb) {
    int t = threadIdx.x;
    if (t >= COUT * 3) return;
    int co = t / 3, k = t % 3;
    uint32_t nz = 0, sn = 0;
    #pragma unroll
    for (int ci = 0; ci < CIN; ++ci) {
        float v = w[(co * CIN + ci) * 3 + k];
        nz |= ((uint32_t)(v != 0.0f)) << ci;
        sn |= ((uint32_t)(v < 0.0f)) << ci;
    }
    wb[co * 8 + k * 2 + 0] = nz;
    wb[co * 8 + k * 2 + 1] = sn;
}

// ---------------- kernel 2: fused pack + ternary conv -------------------------
// grid = NB*NT blocks, 256 threads. Wave g (=t>>6) packs ci-group [8g,8g+8)
// for 4 positions/thread (8 float4 loads), then serves co-group [8g,8g+8) in
// conv. Group mask words are OR-combined into `fin` between two barriers.
// Pair layout: position p (local, -1..TILE) at pair index p+1, words
// {nz, sign} interleaved.
#define TAP(nzx, snx, wz, ws) \
    { uint32_t t1 = (nzx) & (wz); uint32_t t2 = ((snx) ^ (ws)) & t1; \
      P += __popc(t1); Q += __popc(t2); }

__global__ __launch_bounds__(256, 8) void fused_kernel(const float* __restrict__ x,
                                                       const uint32_t* __restrict__ wb,
                                                       const float* __restrict__ osc,
                                                       const float* __restrict__ lsc,
                                                       float* __restrict__ out) {
    __shared__ uint32_t grp[4][(TILE + 2) * 2];   // 8256 B
    __shared__ uint32_t fin[(TILE + 2) * 2];      // 2064 B

    const int b  = blockIdx.x;
    const int n  = b >> 3;
    const int l0 = (b & 7) * TILE;
    const int t  = threadIdx.x;
    const int g  = __builtin_amdgcn_readfirstlane(t >> 6);  // wave index 0..3
    const int q  = t & 63;
    const float* xn = x + (size_t)n * (CIN * LL);

    // ---- pack main: positions 4q..4q+3, ci in [8g, 8g+8)
    {
        const int lb = l0 + 4 * q;
        uint32_t nz0=0,sn0=0,nz1=0,sn1=0,nz2=0,sn2=0,nz3=0,sn3=0;
        if (lb < LL) {   // 4 | LL, so quads are all-in or all-out
            const uint32_t bit0 = 1u << (8 * g);
            #pragma unroll
            for (int j = 0; j < 8; ++j) {
                const uint32_t m = bit0 << j;
                float4 v = *(const float4*)(xn + (size_t)(8 * g + j) * LL + lb);
                if (v.x != 0.0f) nz0 |= m;   if (v.x < 0.0f) sn0 |= m;
                if (v.y != 0.0f) nz1 |= m;   if (v.y < 0.0f) sn1 |= m;
                if (v.z != 0.0f) nz2 |= m;   if (v.z < 0.0f) sn2 |= m;
                if (v.w != 0.0f) nz3 |= m;   if (v.w < 0.0f) sn3 |= m;
            }
        }
        uint32_t* dst = &grp[g][2 * (4 * q + 1)];
        *(uint2*)(dst + 0) = make_uint2(nz0, sn0);
        *(uint2*)(dst + 2) = make_uint2(nz1, sn1);
        *(uint2*)(dst + 4) = make_uint2(nz2, sn2);
        *(uint2*)(dst + 6) = make_uint2(nz3, sn3);
    }
    // ---- halo: threads 0..7 -> (group, left/right)
    if (t < 8) {
        const int  gg    = t & 3;
        const bool right = t >= 4;
        const int  l     = right ? (l0 + TILE) : (l0 - 1);
        uint32_t nz = 0, sn = 0;
        if (l >= 0 && l < LL) {
            #pragma unroll
            for (int j = 0; j < 8; ++j) {
                float v = xn[(size_t)(8 * gg + j) * LL + l];
                if (v != 0.0f) nz |= 1u << (8 * gg + j);
                if (v < 0.0f)  sn |= 1u << (8 * gg + j);
            }
        }
        const int pi = right ? (TILE + 1) : 0;
        grp[gg][2 * pi]     = nz;
        grp[gg][2 * pi + 1] = sn;
    }
    __syncthreads();
    // ---- combine 4 group arrays
    for (int i = t; i < (TILE + 2) * 2; i += 256)
        fin[i] = grp[0][i] | grp[1][i] | grp[2][i] | grp[3][i];
    __syncthreads();

    // ---- conv: positions 4q..4q+3, co in [8g, 8g+8)
    const int l = l0 + 4 * q;
    if (l >= LL) return;
    const uint4 A = *(const uint4*)&fin[8 * q];       // (nz,sn)@p-1, @p
    const uint4 B = *(const uint4*)&fin[8 * q + 4];   // @p+1, @p+2
    const uint4 C = *(const uint4*)&fin[8 * q + 8];   // @p+3, @p+4
    const float4 ls = *(const float4*)(lsc + l);
    float* o = out + (size_t)n * (COUT * LL) + l;

    #pragma unroll
    for (int j = 0; j < 8; ++j) {
        const int co = 8 * g + j;
        const uint32_t wz0 = wb[co*8+0], ws0 = wb[co*8+1];
        const uint32_t wz1 = wb[co*8+2], ws1 = wb[co*8+3];
        const uint32_t wz2 = wb[co*8+4], ws2 = wb[co*8+5];
        const float os = osc[co];

        int P = 0, Q = 0;
        TAP(A.x, A.y, wz0, ws0) TAP(A.z, A.w, wz1, ws1) TAP(B.x, B.y, wz2, ws2)
        const int d0 = P - 2 * Q;
        P = 0; Q = 0;
        TAP(A.z, A.w, wz0, ws0) TAP(B.x, B.y, wz1, ws1) TAP(B.z, B.w, wz2, ws2)
        const int d1 = P - 2 * Q;
        P = 0; Q = 0;
        TAP(B.x, B.y, wz0, ws0) TAP(B.z, B.w, wz1, ws1) TAP(C.x, C.y, wz2, ws2)
        const int d2 = P - 2 * Q;
        P = 0; Q = 0;
        TAP(B.z, B.w, wz0, ws0) TAP(C.x, C.y, wz1, ws1) TAP(C.z, C.w, wz2, ws2)
        const int d3 = P - 2 * Q;

        float4 r;
        r.x = (float)d0 * os * ls.x;
        r.y = (float)d1 * os * ls.y;
        r.z = (float)d2 * os * ls.z;
        r.w = (float)d3 * os * ls.w;
        *(float4*)(o + (size_t)co * LL) = r;
    }
}

extern "C" void kernel_launch(void* const* d_in, const int* in_sizes, int n_in,
                              void* d_out, int out_size, void* d_ws, size_t ws_size,
                              hipStream_t stream) {
    const float* x   = (const float*)d_in[0];
    const float* w   = (const float*)d_in[1];
    const float* osc = (const float*)d_in[2];
    const float* lsc = (const float*)d_in[3];
    float* out = (float*)d_out;

    uint32_t* wb = (uint32_t*)d_ws;   // 1 KiB used

    pack_w_kernel<<<1, 96, 0, stream>>>(w, wb);
    fused_kernel<<<NB * NT, 256, 0, stream>>>(x, wb, osc, lsc, out);
}